// Round 2
// baseline (483.389 us; speedup 1.0000x reference)
//
#include <hip/hip_runtime.h>
#include <stdint.h>

// EfficientInteractionBilinear: out[e,o] = sum_{i,h} (rbf_W1[e] @ sph[e] @ m2[e])[i,h] * W[h,i,o]
// Decomposition (adaptively chunked over edges so the A intermediate fits ws_size):
//   prep:  inv[e,k] = t  (inverse of ragged scatter);  W2T[o][c=i*128+h] = bf16(W[h,i,o])
//   per chunk of EC edges:
//     pass1: per-edge fp32: sum_k = sph@m2 ; A[i,h] = rbf@sum_k  -> bf16 ws (c = i*128+h)
//     pass2: bf16 MFMA GEMM: out[e,o] = sum_c A'[e,c] * W2T[o][c]   (M=EC,K=8192,N=128)

#define EMB 128
#define INTERM 64
#define SPH 16
#define KMAX 8
#define OUTD 128
#define KDIM 8192  // INTERM*EMB

typedef __attribute__((ext_vector_type(8))) short bf16x8;
typedef __attribute__((ext_vector_type(4))) float f32x4;

__device__ __forceinline__ unsigned short f32_to_bf16(float f) {
  union { float f; uint32_t u; } v; v.f = f;
  uint32_t r = (v.u + 0x7fffu + ((v.u >> 16) & 1u)) >> 16;
  return (unsigned short)r;
}

// ---- build inverse ragged index: inv[e*K + k] = t ----
__global__ void k_build_inv(const int* __restrict__ id_reduce,
                            const int* __restrict__ id_ragged,
                            int* __restrict__ inv, int nTrip, int E) {
  int t = blockIdx.x * blockDim.x + threadIdx.x;
  if (t >= nTrip) return;
  int e = id_reduce[t], k = id_ragged[t];
  if (e >= 0 && e < E && k >= 0 && k < KMAX) inv[e * KMAX + k] = t;
}

// ---- W (h,i,o) f32 -> W2T[o][c = i*128 + h] bf16 ----
__global__ void k_w2t(const float* __restrict__ W, unsigned short* __restrict__ W2T) {
  int idx = blockIdx.x * blockDim.x + threadIdx.x;  // [0, 128*8192)
  int o = idx >> 13;
  int c = idx & (KDIM - 1);
  int h = c & 127, i = c >> 7;
  W2T[idx] = f32_to_bf16(W[(h * INTERM + i) * OUTD + o]);
}

// ---- pass1: per-edge fp32 chain, write A bf16 [local_e][i*128+h] ----
__global__ __launch_bounds__(256) void k_pass1(
    const float* __restrict__ rbf,   // [E][64][16]
    const float* __restrict__ sph,   // [E][16][8]
    const float* __restrict__ m,     // [nTrip][128]
    const int* __restrict__ inv,     // [E][8]
    unsigned short* __restrict__ A,  // [chunk_pad][8192] bf16
    int e_base)
{
  int el = blockIdx.x;             // local row in chunk
  int e = e_base + el;             // global edge
  int tid = threadIdx.x;
  __shared__ float s_m[KMAX][EMB];       // 4 KB
  __shared__ float s_sph[SPH][KMAX];     // 0.5 KB
  __shared__ float s_rbf[INTERM][SPH];   // 4 KB
  __shared__ float s_sumk[EMB][20];      // [h][s] padded, 10 KB

  // vectorized loads
  {
    int k = tid >> 5, h4 = tid & 31;   // 8 rows x 32 float4
    int t = inv[e * KMAX + k];
    float4 mv = make_float4(0.f, 0.f, 0.f, 0.f);
    if (t >= 0) mv = ((const float4*)(m + (size_t)t * EMB))[h4];
    ((float4*)(&s_m[k][0]))[h4] = mv;
    ((float4*)(&s_rbf[0][0]))[tid] = ((const float4*)(rbf + (size_t)e * 1024))[tid];
    if (tid < 32) ((float4*)(&s_sph[0][0]))[tid] = ((const float4*)(sph + (size_t)e * 128))[tid];
  }
  __syncthreads();

  int h = tid & 127;
  int half = tid >> 7;

  // sum_k[s][h] = sum_k sph[s][k] * m2[k][h]; stored transposed as s_sumk[h][s]
  {
    float mreg[8];
#pragma unroll
    for (int k = 0; k < 8; ++k) mreg[k] = s_m[k][h];
#pragma unroll
    for (int ss = 0; ss < 8; ++ss) {
      int s = half * 8 + ss;
      const float4* sp4 = (const float4*)(&s_sph[s][0]);
      float4 p0 = sp4[0], p1 = sp4[1];
      float acc = p0.x * mreg[0] + p0.y * mreg[1] + p0.z * mreg[2] + p0.w * mreg[3]
                + p1.x * mreg[4] + p1.y * mreg[5] + p1.z * mreg[6] + p1.w * mreg[7];
      s_sumk[h][s] = acc;
    }
  }
  __syncthreads();

  // A[i][h] = sum_s rbf[i][s] * sum_k[s][h]
  {
    float sk[16];
    const float4* sk4 = (const float4*)(&s_sumk[h][0]);
#pragma unroll
    for (int s4 = 0; s4 < 4; ++s4) {
      float4 v = sk4[s4];
      sk[s4 * 4 + 0] = v.x; sk[s4 * 4 + 1] = v.y; sk[s4 * 4 + 2] = v.z; sk[s4 * 4 + 3] = v.w;
    }
    unsigned short* Arow = A + (size_t)el * KDIM + h;
#pragma unroll
    for (int ii = 0; ii < 32; ++ii) {
      int i = half * 32 + ii;
      const float4* rb4 = (const float4*)(&s_rbf[i][0]);
      float acc = 0.f;
#pragma unroll
      for (int s4 = 0; s4 < 4; ++s4) {
        float4 rv = rb4[s4];
        acc += rv.x * sk[s4 * 4 + 0] + rv.y * sk[s4 * 4 + 1]
             + rv.z * sk[s4 * 4 + 2] + rv.w * sk[s4 * 4 + 3];
      }
      Arow[(size_t)i * EMB] = f32_to_bf16(acc);
    }
  }
}

// ---- pass2: GEMM out[e][o] = sum_c A'[e][c] * W'[c][o] via bf16 MFMA ----
#define BM 64
#define BK 64
#define LDK 72  // padded row stride in ushorts (kills pow2 bank conflicts)

__global__ __launch_bounds__(256) void k_pass2(
    const unsigned short* __restrict__ A,    // [chunk_pad][8192]
    const unsigned short* __restrict__ W2T,  // [128][8192]
    float* __restrict__ out, int e_base, int nrows)
{
  __shared__ unsigned short s_a[BM * LDK];   // 9 KB
  __shared__ unsigned short s_b[OUTD * LDK]; // 18 KB
  int tid = threadIdx.x;
  int e0 = blockIdx.x * BM;                  // local row base
  int wid = tid >> 6, lane = tid & 63;
  int wm = wid >> 1, wn = wid & 1;     // 2x2 wave grid; wave tile 32x64
  int lr = lane & 15, lg = lane >> 4;

  f32x4 acc[2][4];
#pragma unroll
  for (int i = 0; i < 2; ++i)
#pragma unroll
    for (int j = 0; j < 4; ++j) acc[i][j] = (f32x4){0.f, 0.f, 0.f, 0.f};

  for (int kc = 0; kc < KDIM; kc += BK) {
    // stage A tile: 64 rows x 64 k = 512 x (8 bf16) chunks
#pragma unroll
    for (int j = 0; j < 2; ++j) {
      int q = tid + 256 * j;
      int r = q >> 3, c8 = q & 7;
      uint4 v = *(const uint4*)(A + (size_t)(e0 + r) * KDIM + kc + c8 * 8);
      *(uint4*)(&s_a[r * LDK + c8 * 8]) = v;
    }
    // stage B tile: 128 rows (o) x 64 k
#pragma unroll
    for (int j = 0; j < 4; ++j) {
      int q = tid + 256 * j;
      int o = q >> 3, c8 = q & 7;
      uint4 v = *(const uint4*)(W2T + (size_t)o * KDIM + kc + c8 * 8);
      *(uint4*)(&s_b[o * LDK + c8 * 8]) = v;
    }
    __syncthreads();

#pragma unroll
    for (int ks = 0; ks < 2; ++ks) {
      bf16x8 af[2], bfr[4];
#pragma unroll
      for (int mf = 0; mf < 2; ++mf) {
        int row = wm * 32 + mf * 16 + lr;
        af[mf] = *(const bf16x8*)(&s_a[row * LDK + ks * 32 + lg * 8]);
      }
#pragma unroll
      for (int nf = 0; nf < 4; ++nf) {
        int o = wn * 64 + nf * 16 + lr;
        bfr[nf] = *(const bf16x8*)(&s_b[o * LDK + ks * 32 + lg * 8]);
      }
#pragma unroll
      for (int mf = 0; mf < 2; ++mf)
#pragma unroll
        for (int nf = 0; nf < 4; ++nf)
          acc[mf][nf] = __builtin_amdgcn_mfma_f32_16x16x32_bf16(af[mf], bfr[nf], acc[mf][nf], 0, 0, 0);
    }
    __syncthreads();
  }

  // epilogue: C/D layout col = lane&15, row = (lane>>4)*4 + reg
#pragma unroll
  for (int mf = 0; mf < 2; ++mf) {
#pragma unroll
    for (int r = 0; r < 4; ++r) {
      int rl = e0 + wm * 32 + mf * 16 + lg * 4 + r;  // local row
      if (rl < nrows) {
#pragma unroll
        for (int nf = 0; nf < 4; ++nf) {
          int col = wn * 64 + nf * 16 + lr;
          out[(size_t)(e_base + rl) * OUTD + col] = acc[mf][nf][r];
        }
      }
    }
  }
}

extern "C" void kernel_launch(void* const* d_in, const int* in_sizes, int n_in,
                              void* d_out, int out_size, void* d_ws, size_t ws_size,
                              hipStream_t stream) {
  const float* rbf = (const float*)d_in[0];
  const float* sph = (const float*)d_in[1];
  const float* m   = (const float*)d_in[2];
  const float* W   = (const float*)d_in[3];
  const int* id_reduce = (const int*)d_in[4];
  const int* id_ragged = (const int*)d_in[5];
  float* out = (float*)d_out;

  int E = in_sizes[0] / (INTERM * SPH);   // 30000
  int nTrip = in_sizes[2] / EMB;          // 240000

  char* ws = (char*)d_ws;
  int* inv = (int*)ws;                                           // < 1 MB
  unsigned short* W2T = (unsigned short*)(ws + (1u << 20));      // 2 MB
  const size_t A_off = 3u << 20;
  unsigned short* A = (unsigned short*)(ws + A_off);

  // edges per chunk, multiple of BM, as large as ws allows
  size_t avail = ws_size > A_off ? ws_size - A_off : 0;
  long long ecll = (long long)(avail / ((size_t)KDIM * sizeof(unsigned short)));
  int ec = (int)((ecll > 4000000LL) ? 4000000LL : ecll);
  ec = (ec / BM) * BM;
  int e_pad_total = ((E + BM - 1) / BM) * BM;
  if (ec > e_pad_total) ec = e_pad_total;
  if (ec < BM) ec = BM;  // last resort (assumes ws >= ~4 MB)

  hipMemsetAsync(inv, 0xFF, (size_t)E * KMAX * sizeof(int), stream);
  k_build_inv<<<(nTrip + 255) / 256, 256, 0, stream>>>(id_reduce, id_ragged, inv, nTrip, E);
  k_w2t<<<(OUTD * KDIM) / 256, 256, 0, stream>>>(W, W2T);

  for (int e_base = 0; e_base < E; e_base += ec) {
    int n = E - e_base; if (n > ec) n = ec;
    int nblk = (n + BM - 1) / BM;
    int npad = nblk * BM;
    if (npad > n)
      hipMemsetAsync(A + (size_t)n * KDIM, 0,
                     (size_t)(npad - n) * KDIM * sizeof(unsigned short), stream);
    k_pass1<<<n, 256, 0, stream>>>(rbf, sph, m, inv, A, e_base);
    k_pass2<<<nblk, 256, 0, stream>>>(A, W2T, out, e_base, n);
  }
}

// Round 3
// 456.698 us; speedup vs baseline: 1.0584x; 1.0584x over previous
//
#include <hip/hip_runtime.h>
#include <stdint.h>

// out[e,o] = sum_{i,h} A[e,i,h] * W[h,i,o],  A[e] = rbf[e] @ sph[e] @ m2[e]
// Fused: rs[e,i,k] = sum_s rbf[e,i,s] sph[e,s,k]  (per-block, LDS bf16)
//        A_i[e,h]  = sum_k rs[e,i,k] m2[e,k,h]    (VALU, m2 in regs, -> swizzled LDS)
//        out      += A_i @ W_i                     (MFMA 16x16x32 bf16, W dbuf via global_load_lds)

#define EMB 128
#define INTERM 64
#define SPH_N 16
#define KMAX 8
#define OUTD 128
#define KDIM 8192
#define EB 64
#define NTHR 1024

typedef __attribute__((ext_vector_type(8))) short bf16x8;
typedef __attribute__((ext_vector_type(4))) float f32x4;

__device__ __forceinline__ unsigned short f32_to_bf16(float f) {
  union { float f; uint32_t u; } v; v.f = f;
  uint32_t r = (v.u + 0x7fffu + ((v.u >> 16) & 1u)) >> 16;
  return (unsigned short)r;
}

__device__ __forceinline__ uint32_t cvtpk_bf16(float lo, float hi) {
  uint32_t r;
  asm("v_cvt_pk_bf16_f32 %0, %1, %2" : "=v"(r) : "v"(lo), "v"(hi));
  return r;
}

__device__ __forceinline__ void bar() {
  asm volatile("" ::: "memory");
  __builtin_amdgcn_s_barrier();
  asm volatile("" ::: "memory");
}

// ---- build inverse ragged index: inv[e*K + k] = t ----
__global__ void k_build_inv(const int* __restrict__ id_reduce,
                            const int* __restrict__ id_ragged,
                            int* __restrict__ inv, int nTrip, int E) {
  int t = blockIdx.x * blockDim.x + threadIdx.x;
  if (t >= nTrip) return;
  int e = id_reduce[t], k = id_ragged[t];
  if (e >= 0 && e < E && k >= 0 && k < KMAX) inv[e * KMAX + k] = t;
}

// ---- W (h,i,o) f32 -> W2T[o][c = i*128 + h] bf16 ----
__global__ void k_w2t(const float* __restrict__ W, unsigned short* __restrict__ W2T) {
  int idx = blockIdx.x * blockDim.x + threadIdx.x;  // [0, 128*8192)
  int o = idx >> 13;
  int c = idx & (KDIM - 1);
  int h = c & 127, i = c >> 7;
  W2T[idx] = f32_to_bf16(W[(h * INTERM + i) * OUTD + o]);
}

// ---- W slab prefetch: linear LDS dest, pre-swizzled global source ----
__device__ __forceinline__ void w_prefetch(unsigned short* buf,
                                           const unsigned short* __restrict__ W2T,
                                           int i, int wid, int lane) {
#pragma unroll
  for (int j = 0; j < 2; ++j) {
    int dbase = j * 8192 + wid * 512;          // wave-uniform dest elem base
    int d = dbase + lane * 8;                  // this lane's dest elem
    int o = d >> 7, c0 = d & 127;
    const unsigned short* g = W2T + (size_t)o * KDIM + i * 128 + (c0 ^ ((o & 7) << 3));
    __builtin_amdgcn_global_load_lds(
        (const __attribute__((address_space(1))) unsigned int*)g,
        (__attribute__((address_space(3))) unsigned int*)(buf + dbase),
        16, 0, 0);
  }
}

__global__ __launch_bounds__(NTHR) void k_fused(
    const float* __restrict__ rbf,   // [E][64][16]
    const float* __restrict__ sph,   // [E][16][8]
    const float* __restrict__ m,     // [nTrip][128]
    const int* __restrict__ inv,     // [E][8]
    const unsigned short* __restrict__ W2T,  // [128][8192]
    float* __restrict__ out, int E)
{
  __shared__ unsigned short s_rs[EB * 64 * 8];   // 64 KB bf16 rs[e][i][k]
  __shared__ unsigned short s_A[EB * 128];       // 16 KB  A_i, xor-swizzled rows
  __shared__ unsigned short s_W[2][128 * 128];   // 64 KB  W dbuf, xor-swizzled rows

  int tid = threadIdx.x;
  int e0 = blockIdx.x * EB;
  int wid = tid >> 6, lane = tid & 63;
  int eL = tid >> 4;        // 0..63 edge-local
  int hg = tid & 15;        // h-group of 8

  // ---- P0: stage sph block into s_W[1] area (fp32), issue W_0 prefetch, m2 -> regs
  float* s_sph = (float*)&s_W[1][0];             // 8192 floats = 32 KB
  {
#pragma unroll
    for (int j = 0; j < 2; ++j) {
      int idx = tid + j * 1024;                  // float4 index
      int ee = idx >> 5, c4 = idx & 31;
      float4 v = make_float4(0.f, 0.f, 0.f, 0.f);
      if (e0 + ee < E) v = ((const float4*)(sph + (size_t)(e0 + ee) * 128))[c4];
      ((float4*)s_sph)[idx] = v;
    }
  }
  w_prefetch(&s_W[0][0], W2T, 0, wid, lane);     // W_0 in flight under prolog

  float m2r[8][8];
  {
    int eg = e0 + eL;
#pragma unroll
    for (int k = 0; k < 8; ++k) {
      float4 a = make_float4(0.f, 0.f, 0.f, 0.f), b = a;
      if (eg < E) {
        int t = inv[eg * KMAX + k];
        if (t >= 0) {
          const float4* mp = (const float4*)(m + (size_t)t * EMB + hg * 8);
          a = mp[0]; b = mp[1];
        }
      }
      m2r[k][0] = a.x; m2r[k][1] = a.y; m2r[k][2] = a.z; m2r[k][3] = a.w;
      m2r[k][4] = b.x; m2r[k][5] = b.y; m2r[k][6] = b.z; m2r[k][7] = b.w;
    }
  }
  asm volatile("s_waitcnt lgkmcnt(0)" ::: "memory");
  bar();   // sph visible (W_0 still in flight)

  // ---- P1: rs[e][i][k] = sum_s rbf[e][i][s] * sph[e][s][k]  -> LDS bf16
  {
    int eg = e0 + eL;
#pragma unroll
    for (int u = 0; u < 4; ++u) {
      int i = hg + u * 16;
      float rsk[8] = {0.f, 0.f, 0.f, 0.f, 0.f, 0.f, 0.f, 0.f};
      if (eg < E) {
        const float4* rb = (const float4*)(rbf + ((size_t)eg * INTERM + i) * SPH_N);
        float4 r0 = rb[0], r1 = rb[1], r2 = rb[2], r3 = rb[3];
        float rv[16] = {r0.x, r0.y, r0.z, r0.w, r1.x, r1.y, r1.z, r1.w,
                        r2.x, r2.y, r2.z, r2.w, r3.x, r3.y, r3.z, r3.w};
#pragma unroll
        for (int s = 0; s < 16; ++s) {
          const float* sp = s_sph + (eL * 16 + s) * 8;
#pragma unroll
          for (int k = 0; k < 8; ++k) rsk[k] += rv[s] * sp[k];
        }
      }
      uint32_t p0 = cvtpk_bf16(rsk[0], rsk[1]);
      uint32_t p1 = cvtpk_bf16(rsk[2], rsk[3]);
      uint32_t p2 = cvtpk_bf16(rsk[4], rsk[5]);
      uint32_t p3 = cvtpk_bf16(rsk[6], rsk[7]);
      uint4 pk = make_uint4(p0, p1, p2, p3);
      *(uint4*)&s_rs[(eL * 64 + i) * 8] = pk;
    }
  }
  asm volatile("s_waitcnt lgkmcnt(0)" ::: "memory");
  bar();   // rs visible; sph dead (s_W[1] reusable from i=0's prefetch of W_1)

  // ---- i-loop: A_i on VALU -> swizzled LDS; MFMA with W_i; prefetch W_{i+1}
  int eh = wid >> 2, oq = wid & 3;
  int lr = lane & 15, lg = lane >> 4;
  f32x4 acc[2];
  acc[0] = (f32x4){0.f, 0.f, 0.f, 0.f};
  acc[1] = (f32x4){0.f, 0.f, 0.f, 0.f};

  for (int i = 0; i < 64; ++i) {
    int cur = i & 1, nxt = cur ^ 1;

    // A_i[e][h] for this thread's 8 h-values
    uint4 rr = *(const uint4*)&s_rs[(eL * 64 + i) * 8];
    float rf[8];
    rf[0] = __uint_as_float(rr.x << 16); rf[1] = __uint_as_float(rr.x & 0xffff0000u);
    rf[2] = __uint_as_float(rr.y << 16); rf[3] = __uint_as_float(rr.y & 0xffff0000u);
    rf[4] = __uint_as_float(rr.z << 16); rf[5] = __uint_as_float(rr.z & 0xffff0000u);
    rf[6] = __uint_as_float(rr.w << 16); rf[7] = __uint_as_float(rr.w & 0xffff0000u);
    float a[8];
#pragma unroll
    for (int j = 0; j < 8; ++j) {
      float acc_a = rf[0] * m2r[0][j];
#pragma unroll
      for (int k = 1; k < 8; ++k) acc_a += rf[k] * m2r[k][j];
      a[j] = acc_a;
    }
    uint4 pa = make_uint4(cvtpk_bf16(a[0], a[1]), cvtpk_bf16(a[2], a[3]),
                          cvtpk_bf16(a[4], a[5]), cvtpk_bf16(a[6], a[7]));

    bar();   // #1: previous MFMA done reading s_A and s_W[nxt]

    *(uint4*)&s_A[eL * 128 + ((hg * 8) ^ ((eL & 7) << 3))] = pa;
    if (i < 63) w_prefetch(&s_W[nxt][0], W2T, i + 1, wid, lane);
    if (i < 63) asm volatile("s_waitcnt vmcnt(2) lgkmcnt(0)" ::: "memory");
    else        asm volatile("s_waitcnt vmcnt(0) lgkmcnt(0)" ::: "memory");
    bar();   // #2: A_i and W_i visible

    const unsigned short* Wb = &s_W[cur][0];
#pragma unroll
    for (int ks = 0; ks < 4; ++ks) {
      int arow = eh * 16 + lr;
      bf16x8 af = *(const bf16x8*)&s_A[arow * 128 + ((ks * 32 + lg * 8) ^ ((arow & 7) << 3))];
#pragma unroll
      for (int nf = 0; nf < 2; ++nf) {
        int o = oq * 32 + nf * 16 + lr;
        bf16x8 bv = *(const bf16x8*)&Wb[o * 128 + ((ks * 32 + lg * 8) ^ ((o & 7) << 3))];
        acc[nf] = __builtin_amdgcn_mfma_f32_16x16x32_bf16(af, bv, acc[nf], 0, 0, 0);
      }
    }
  }

  // ---- epilogue: C/D layout col = lane&15, row = (lane>>4)*4 + reg
  int row0 = e0 + eh * 16 + lg * 4;
#pragma unroll
  for (int nf = 0; nf < 2; ++nf) {
    int col = oq * 32 + nf * 16 + lr;
#pragma unroll
    for (int r = 0; r < 4; ++r) {
      int row = row0 + r;
      if (row < E) out[(size_t)row * OUTD + col] = acc[nf][r];
    }
  }
}

extern "C" void kernel_launch(void* const* d_in, const int* in_sizes, int n_in,
                              void* d_out, int out_size, void* d_ws, size_t ws_size,
                              hipStream_t stream) {
  const float* rbf = (const float*)d_in[0];
  const float* sph = (const float*)d_in[1];
  const float* m   = (const float*)d_in[2];
  const float* W   = (const float*)d_in[3];
  const int* id_reduce = (const int*)d_in[4];
  const int* id_ragged = (const int*)d_in[5];
  float* out = (float*)d_out;

  int E = in_sizes[0] / (INTERM * SPH_N);   // 30000
  int nTrip = in_sizes[2] / EMB;            // 240000

  char* ws = (char*)d_ws;
  int* inv = (int*)ws;                                       // <1 MB
  unsigned short* W2T = (unsigned short*)(ws + (1u << 20));  // 2 MB

  hipMemsetAsync(inv, 0xFF, (size_t)E * KMAX * sizeof(int), stream);
  k_build_inv<<<(nTrip + 255) / 256, 256, 0, stream>>>(id_reduce, id_ragged, inv, nTrip, E);
  k_w2t<<<(OUTD * KDIM) / 256, 256, 0, stream>>>(W, W2T);

  int nblk = (E + EB - 1) / EB;   // 469
  k_fused<<<nblk, NTHR, 0, stream>>>(rbf, sph, m, inv, W2T, out, E);
}

// Round 4
// 299.994 us; speedup vs baseline: 1.6113x; 1.5224x over previous
//
#include <hip/hip_runtime.h>
#include <stdint.h>

// out[e,o] = sum_{i,h} A[e,i,h] * W[h,i,o],  A[e] = rbf[e] @ sph[e] @ m2[e]
// Fully fused, K-chunked as (hw outer 0..3, i inner 0..63), chunk = 32 h:
//   prolog: rs[e,i,k] = sum_s rbf[e,i,s] sph[e,s,k]  -> LDS bf16 (swizzled)
//   per chunk: A_c[e, 32h] = sum_k rs[e,i,k] m2[e,k,hw*32+h]  (VALU, m2-slice in regs)
//              acc += A_c @ W_c   (mfma 16x16x32 bf16; W B-frags global->VGPR dbuf)
// 1 barrier/chunk, A double-buffered in LDS, W never touches LDS.

#define EMB 128
#define INTERM 64
#define SPH_N 16
#define KMAX 8
#define OUTD 128
#define KDIM 8192
#define EB 64
#define NTHR 512
#define NCHUNK 256

typedef __attribute__((ext_vector_type(8))) short bf16x8;
typedef __attribute__((ext_vector_type(4))) float f32x4;

__device__ __forceinline__ unsigned short f32_to_bf16(float f) {
  union { float f; uint32_t u; } v; v.f = f;
  uint32_t r = (v.u + 0x7fffu + ((v.u >> 16) & 1u)) >> 16;
  return (unsigned short)r;
}
__device__ __forceinline__ uint32_t cvtpk_bf16(float lo, float hi) {
  uint32_t r;
  asm("v_cvt_pk_bf16_f32 %0, %1, %2" : "=v"(r) : "v"(lo), "v"(hi));
  return r;
}
__device__ __forceinline__ float bf16lo_f(uint32_t u) { return __uint_as_float(u << 16); }
__device__ __forceinline__ float bf16hi_f(uint32_t u) { return __uint_as_float(u & 0xffff0000u); }

// ---- build inverse ragged index: inv[e*K + k] = t ----
__global__ void k_build_inv(const int* __restrict__ id_reduce,
                            const int* __restrict__ id_ragged,
                            int* __restrict__ inv, int nTrip, int E) {
  int t = blockIdx.x * blockDim.x + threadIdx.x;
  if (t >= nTrip) return;
  int e = id_reduce[t], k = id_ragged[t];
  if (e >= 0 && e < E && k >= 0 && k < KMAX) inv[e * KMAX + k] = t;
}

// ---- W (h,i,o) f32 -> W2T[o][c = i*128 + h] bf16 ----
__global__ void k_w2t(const float* __restrict__ W, unsigned short* __restrict__ W2T) {
  int idx = blockIdx.x * blockDim.x + threadIdx.x;  // [0, 128*8192)
  int o = idx >> 13;
  int c = idx & (KDIM - 1);
  int h = c & 127, i = c >> 7;
  W2T[idx] = f32_to_bf16(W[(h * INTERM + i) * OUTD + o]);
}

__global__ __launch_bounds__(NTHR, 4) void k_fused(
    const float* __restrict__ rbf,   // [E][64][16]
    const float* __restrict__ sph,   // [E][16][8]
    const float* __restrict__ m,     // [nTrip][128]
    const int* __restrict__ inv,     // [E][8]
    const unsigned short* __restrict__ W2T,  // [128][8192]
    float* __restrict__ out, int E)
{
  __shared__ unsigned short s_rs[EB * 64 * 8];  // 64 KB, rs[e][i][k] swizzled
  __shared__ unsigned short s_A[2][EB * 32];    // 2 x 4 KB, A-chunk dbuf swizzled

  int tid = threadIdx.x;
  int e0 = blockIdx.x * EB;

  int eL = tid >> 3;          // 0..63: edge-local (both roles)
  int kq = tid & 7;           // prolog role: k index
  int hq = tid & 7;           // main role: h-quarter (4 h)
  int eg = e0 + eL;
  bool ev = (eg < E);
  int esw8 = (eL & 7) << 3;   // rs swizzle (ushort units)
  int asw  = (eL & 3) << 3;   // A swizzle (ushort units)

  // ---- prolog: rs[e][i][kq] for all i (broadcast rbf rows over the 8 kq lanes)
  {
    float sphc[16];
#pragma unroll
    for (int s = 0; s < 16; ++s)
      sphc[s] = ev ? sph[(size_t)eg * 128 + s * 8 + kq] : 0.f;
    const float4* rb = (const float4*)(rbf + (size_t)eg * 1024);
#pragma unroll 4
    for (int i = 0; i < 64; ++i) {
      float v = 0.f;
      if (ev) {
        float4 q0 = rb[i * 4 + 0], q1 = rb[i * 4 + 1];
        float4 q2 = rb[i * 4 + 2], q3 = rb[i * 4 + 3];
        v = q0.x * sphc[0] + q0.y * sphc[1] + q0.z * sphc[2] + q0.w * sphc[3]
          + q1.x * sphc[4] + q1.y * sphc[5] + q1.z * sphc[6] + q1.w * sphc[7]
          + q2.x * sphc[8] + q2.y * sphc[9] + q2.z * sphc[10] + q2.w * sphc[11]
          + q3.x * sphc[12] + q3.y * sphc[13] + q3.z * sphc[14] + q3.w * sphc[15];
      }
      s_rs[(eL << 9) + (((i << 3) ^ esw8) | kq)] = f32_to_bf16(v);
    }
  }

  // triplet indices for this edge (all 8 k)
  int tv[8];
  if (ev) {
    int4 a = *(const int4*)(inv + (size_t)eg * 8);
    int4 b = *(const int4*)(inv + (size_t)eg * 8 + 4);
    tv[0] = a.x; tv[1] = a.y; tv[2] = a.z; tv[3] = a.w;
    tv[4] = b.x; tv[5] = b.y; tv[6] = b.z; tv[7] = b.w;
  } else {
#pragma unroll
    for (int k = 0; k < 8; ++k) tv[k] = -1;
  }

  // GEMM wave roles: 8 waves = 2 ew x 4 ow, wave tile 32e x 32o
  int wid = tid >> 6, lane = tid & 63;
  int ew = wid >> 2, ow = wid & 3;
  int lr = lane & 15, lg = lane >> 4;
  int aidx0, aidx1;
  {
    int r0 = ew * 32 + lr;
    int r1 = r0 + 16;
    aidx0 = (r0 << 5) + (((lg << 3) ^ ((r0 & 3) << 3)));
    aidx1 = (r1 << 5) + (((lg << 3) ^ ((r1 & 3) << 3)));
  }
  size_t bvb0 = (size_t)(ow * 32 + lr) * KDIM + lg * 8;
  size_t bvb1 = bvb0 + (size_t)16 * KDIM;

  float m2r[8][4];
#define LOAD_M2(HW)                                                        \
  {                                                                        \
    _Pragma("unroll")                                                      \
    for (int k = 0; k < 8; ++k) {                                          \
      float4 v = make_float4(0.f, 0.f, 0.f, 0.f);                          \
      int t = tv[k];                                                       \
      if (t >= 0)                                                          \
        v = *(const float4*)(m + (size_t)t * EMB + (HW) * 32 + hq * 4);    \
      m2r[k][0] = v.x; m2r[k][1] = v.y; m2r[k][2] = v.z; m2r[k][3] = v.w;  \
    }                                                                      \
  }

#define PRODUCE_A(N)                                                        \
  {                                                                         \
    int i_n = (N) & 63;                                                     \
    uint4 rr = *(const uint4*)&s_rs[(eL << 9) + (((i_n << 3) ^ esw8))];     \
    float rf0 = bf16lo_f(rr.x), rf1 = bf16hi_f(rr.x);                       \
    float rf2 = bf16lo_f(rr.y), rf3 = bf16hi_f(rr.y);                       \
    float rf4 = bf16lo_f(rr.z), rf5 = bf16hi_f(rr.z);                       \
    float rf6 = bf16lo_f(rr.w), rf7 = bf16hi_f(rr.w);                       \
    float a0 = 0.f, a1 = 0.f, a2 = 0.f, a3 = 0.f;                           \
    a0 = rf0 * m2r[0][0] + rf1 * m2r[1][0] + rf2 * m2r[2][0] +              \
         rf3 * m2r[3][0] + rf4 * m2r[4][0] + rf5 * m2r[5][0] +              \
         rf6 * m2r[6][0] + rf7 * m2r[7][0];                                 \
    a1 = rf0 * m2r[0][1] + rf1 * m2r[1][1] + rf2 * m2r[2][1] +              \
         rf3 * m2r[3][1] + rf4 * m2r[4][1] + rf5 * m2r[5][1] +              \
         rf6 * m2r[6][1] + rf7 * m2r[7][1];                                 \
    a2 = rf0 * m2r[0][2] + rf1 * m2r[1][2] + rf2 * m2r[2][2] +              \
         rf3 * m2r[3][2] + rf4 * m2r[4][2] + rf5 * m2r[5][2] +              \
         rf6 * m2r[6][2] + rf7 * m2r[7][2];                                 \
    a3 = rf0 * m2r[0][3] + rf1 * m2r[1][3] + rf2 * m2r[2][3] +              \
         rf3 * m2r[3][3] + rf4 * m2r[4][3] + rf5 * m2r[5][3] +              \
         rf6 * m2r[6][3] + rf7 * m2r[7][3];                                 \
    uint32_t p0 = cvtpk_bf16(a0, a1), p1 = cvtpk_bf16(a2, a3);              \
    *(uint2*)&s_A[(N) & 1][(eL << 5) + (((hq << 2) ^ asw))] =               \
        make_uint2(p0, p1);                                                 \
  }

  f32x4 acc[2][2];
#pragma unroll
  for (int a = 0; a < 2; ++a)
#pragma unroll
    for (int b = 0; b < 2; ++b) acc[a][b] = (f32x4){0.f, 0.f, 0.f, 0.f};

  // pipeline fill: m2 slice for hw=0, A-chunk 0, B-frags for chunk 0
  LOAD_M2(0);
  PRODUCE_A(0);
  bf16x8 bvc0, bvc1, bvn0, bvn1;
  bvc0 = *(const bf16x8*)(W2T + bvb0);
  bvc1 = *(const bf16x8*)(W2T + bvb1);
  __syncthreads();

  for (int c = 0; c < NCHUNK; ++c) {
    int n = c + 1;
    if (n < NCHUNK) {
      int co = ((n & 63) << 7) + ((n >> 6) << 5);
      bvn0 = *(const bf16x8*)(W2T + bvb0 + co);
      bvn1 = *(const bf16x8*)(W2T + bvb1 + co);
      if ((n & 63) == 0) LOAD_M2(n >> 6);
      PRODUCE_A(n);
    }
    // MFMA on chunk c
    {
      const unsigned short* Ab = &s_A[c & 1][0];
      bf16x8 af0 = *(const bf16x8*)&Ab[aidx0];
      bf16x8 af1 = *(const bf16x8*)&Ab[aidx1];
      acc[0][0] = __builtin_amdgcn_mfma_f32_16x16x32_bf16(af0, bvc0, acc[0][0], 0, 0, 0);
      acc[0][1] = __builtin_amdgcn_mfma_f32_16x16x32_bf16(af0, bvc1, acc[0][1], 0, 0, 0);
      acc[1][0] = __builtin_amdgcn_mfma_f32_16x16x32_bf16(af1, bvc0, acc[1][0], 0, 0, 0);
      acc[1][1] = __builtin_amdgcn_mfma_f32_16x16x32_bf16(af1, bvc1, acc[1][1], 0, 0, 0);
    }
    bvc0 = bvn0; bvc1 = bvn1;
    __syncthreads();
  }

  // ---- epilogue: C/D layout col = lane&15, row = (lane>>4)*4 + reg
#pragma unroll
  for (int mf = 0; mf < 2; ++mf) {
#pragma unroll
    for (int nf = 0; nf < 2; ++nf) {
      int col = ow * 32 + nf * 16 + lr;
#pragma unroll
      for (int r = 0; r < 4; ++r) {
        int row = e0 + ew * 32 + mf * 16 + lg * 4 + r;
        if (row < E) out[(size_t)row * OUTD + col] = acc[mf][nf][r];
      }
    }
  }
}

extern "C" void kernel_launch(void* const* d_in, const int* in_sizes, int n_in,
                              void* d_out, int out_size, void* d_ws, size_t ws_size,
                              hipStream_t stream) {
  const float* rbf = (const float*)d_in[0];
  const float* sph = (const float*)d_in[1];
  const float* m   = (const float*)d_in[2];
  const float* W   = (const float*)d_in[3];
  const int* id_reduce = (const int*)d_in[4];
  const int* id_ragged = (const int*)d_in[5];
  float* out = (float*)d_out;

  int E = in_sizes[0] / (INTERM * SPH_N);   // 30000
  int nTrip = in_sizes[2] / EMB;            // 240000

  char* ws = (char*)d_ws;
  int* inv = (int*)ws;                                       // <1 MB
  unsigned short* W2T = (unsigned short*)(ws + (1u << 20));  // 2 MB

  hipMemsetAsync(inv, 0xFF, (size_t)E * KMAX * sizeof(int), stream);
  k_build_inv<<<(nTrip + 255) / 256, 256, 0, stream>>>(id_reduce, id_ragged, inv, nTrip, E);
  k_w2t<<<(OUTD * KDIM) / 256, 256, 0, stream>>>(W, W2T);

  int nblk = (E + EB - 1) / EB;   // 469
  k_fused<<<nblk, NTHR, 0, stream>>>(rbf, sph, m, inv, W2T, out, E);
}

// Round 5
// 299.370 us; speedup vs baseline: 1.6147x; 1.0021x over previous
//
#include <hip/hip_runtime.h>
#include <stdint.h>

// out[e,o] = sum_{i,h} A[e,i,h] * W[h,i,o],  A[e] = rbf[e] @ sph[e] @ m2[e]
// Fully fused, chunk c = (hw = c>>6, i = c&63), K=32 per chunk:
//   prolog: rs[e,i,k] = sum_s rbf[e,i,s] sph[e,s,k]  -> LDS bf16 (swizzled)
//   per chunk: A_c[e, 32h] = sum_k rs[e,i,k] m2[e,k,hw*32+h]  (VALU) -> LDS dbuf
//              acc += A_c @ W_c   (mfma 16x16x32 bf16; W global->VGPR, depth-2 prefetch)
// Raw s_barrier + lgkmcnt(0) only (no vmcnt drain); rs prefetched 1 chunk ahead.

#define EMB 128
#define INTERM 64
#define SPH_N 16
#define KMAX 8
#define OUTD 128
#define KDIM 8192
#define EB 64
#define NTHR 512
#define NCHUNK 256

typedef __attribute__((ext_vector_type(8))) short bf16x8;
typedef __attribute__((ext_vector_type(4))) float f32x4;

__device__ __forceinline__ unsigned short f32_to_bf16(float f) {
  union { float f; uint32_t u; } v; v.f = f;
  uint32_t r = (v.u + 0x7fffu + ((v.u >> 16) & 1u)) >> 16;
  return (unsigned short)r;
}
__device__ __forceinline__ uint32_t cvtpk_bf16(float lo, float hi) {
  uint32_t r;
  asm("v_cvt_pk_bf16_f32 %0, %1, %2" : "=v"(r) : "v"(lo), "v"(hi));
  return r;
}
__device__ __forceinline__ float bf16lo_f(uint32_t u) { return __uint_as_float(u << 16); }
__device__ __forceinline__ float bf16hi_f(uint32_t u) { return __uint_as_float(u & 0xffff0000u); }

// ---- build inverse ragged index: inv[e*K + k] = t ----
__global__ void k_build_inv(const int* __restrict__ id_reduce,
                            const int* __restrict__ id_ragged,
                            int* __restrict__ inv, int nTrip, int E) {
  int t = blockIdx.x * blockDim.x + threadIdx.x;
  if (t >= nTrip) return;
  int e = id_reduce[t], k = id_ragged[t];
  if (e >= 0 && e < E && k >= 0 && k < KMAX) inv[e * KMAX + k] = t;
}

// ---- W (h,i,o) f32 -> W2T[o][c = i*128 + h] bf16 ----
__global__ void k_w2t(const float* __restrict__ W, unsigned short* __restrict__ W2T) {
  int idx = blockIdx.x * blockDim.x + threadIdx.x;  // [0, 128*8192)
  int o = idx >> 13;
  int c = idx & (KDIM - 1);
  int h = c & 127, i = c >> 7;
  W2T[idx] = f32_to_bf16(W[(h * INTERM + i) * OUTD + o]);
}

__global__ __launch_bounds__(NTHR, 4) void k_fused(
    const float* __restrict__ rbf,   // [E][64][16]
    const float* __restrict__ sph,   // [E][16][8]
    const float* __restrict__ m,     // [nTrip][128]
    const int* __restrict__ inv,     // [E][8]
    const unsigned short* __restrict__ W2T,  // [128][8192]
    float* __restrict__ out, int E)
{
  __shared__ unsigned short s_rs[EB * 64 * 8];  // 64 KB, rs[e][i][k] swizzled
  __shared__ unsigned short s_A[2][EB * 32];    // 2 x 4 KB, A-chunk dbuf swizzled

  int tid = threadIdx.x;
  int e0 = blockIdx.x * EB;

  int eL = tid >> 3;          // 0..63: edge-local (both roles)
  int kq = tid & 7;           // prolog role: k index
  int hq = tid & 7;           // main role: h-quarter (4 h)
  int eg = e0 + eL;
  bool ev = (eg < E);
  int esw8 = (eL & 7) << 3;   // rs swizzle (ushort units)
  int asw  = (eL & 3) << 3;   // A swizzle (ushort units)

  // ---- prolog: rs[e][i][kq] for all i (8 kq lanes share the rbf row via L1)
  {
    float sphc[16];
#pragma unroll
    for (int s = 0; s < 16; ++s)
      sphc[s] = ev ? sph[(size_t)eg * 128 + s * 8 + kq] : 0.f;
    const float4* rb = (const float4*)(rbf + (size_t)eg * 1024);
#pragma unroll 4
    for (int i = 0; i < 64; ++i) {
      float v = 0.f;
      if (ev) {
        float4 q0 = rb[i * 4 + 0], q1 = rb[i * 4 + 1];
        float4 q2 = rb[i * 4 + 2], q3 = rb[i * 4 + 3];
        v = q0.x * sphc[0] + q0.y * sphc[1] + q0.z * sphc[2] + q0.w * sphc[3]
          + q1.x * sphc[4] + q1.y * sphc[5] + q1.z * sphc[6] + q1.w * sphc[7]
          + q2.x * sphc[8] + q2.y * sphc[9] + q2.z * sphc[10] + q2.w * sphc[11]
          + q3.x * sphc[12] + q3.y * sphc[13] + q3.z * sphc[14] + q3.w * sphc[15];
      }
      s_rs[(eL << 9) + (((i << 3) ^ esw8) | kq)] = f32_to_bf16(v);
    }
  }

  // triplet indices for this edge (all 8 k)
  int tv[8];
  if (ev) {
    int4 a = *(const int4*)(inv + (size_t)eg * 8);
    int4 b = *(const int4*)(inv + (size_t)eg * 8 + 4);
    tv[0] = a.x; tv[1] = a.y; tv[2] = a.z; tv[3] = a.w;
    tv[4] = b.x; tv[5] = b.y; tv[6] = b.z; tv[7] = b.w;
  } else {
#pragma unroll
    for (int k = 0; k < 8; ++k) tv[k] = -1;
  }

  // GEMM wave roles: 8 waves = 2 ew x 4 ow, wave tile 32e x 32o
  int wid = tid >> 6, lane = tid & 63;
  int ew = wid >> 2, ow = wid & 3;
  int lr = lane & 15, lg = lane >> 4;
  int aidx0, aidx1;
  {
    int r0 = ew * 32 + lr;
    int r1 = r0 + 16;
    aidx0 = (r0 << 5) + ((lg << 3) ^ ((r0 & 3) << 3));
    aidx1 = (r1 << 5) + ((lg << 3) ^ ((r1 & 3) << 3));
  }
  size_t bvb0 = (size_t)(ow * 32 + lr) * KDIM + lg * 8;
  size_t bvb1 = bvb0 + (size_t)16 * KDIM;
#define WOFF(c) ((((c) & 63) << 7) + (((c) >> 6) << 5))

  float m2r[8][4];
#define LOAD_M2(HW)                                                        \
  {                                                                        \
    _Pragma("unroll")                                                      \
    for (int k = 0; k < 8; ++k) {                                          \
      float4 v = make_float4(0.f, 0.f, 0.f, 0.f);                          \
      int t = tv[k];                                                       \
      if (t >= 0)                                                          \
        v = *(const float4*)(m + (size_t)t * EMB + (HW) * 32 + hq * 4);    \
      m2r[k][0] = v.x; m2r[k][1] = v.y; m2r[k][2] = v.z; m2r[k][3] = v.w;  \
    }                                                                      \
  }

#define PRODUCE_A_FROM(RR, B)                                               \
  {                                                                         \
    float rf0 = bf16lo_f(RR.x), rf1 = bf16hi_f(RR.x);                       \
    float rf2 = bf16lo_f(RR.y), rf3 = bf16hi_f(RR.y);                       \
    float rf4 = bf16lo_f(RR.z), rf5 = bf16hi_f(RR.z);                       \
    float rf6 = bf16lo_f(RR.w), rf7 = bf16hi_f(RR.w);                       \
    float a0 = rf0 * m2r[0][0] + rf1 * m2r[1][0] + rf2 * m2r[2][0] +        \
               rf3 * m2r[3][0] + rf4 * m2r[4][0] + rf5 * m2r[5][0] +        \
               rf6 * m2r[6][0] + rf7 * m2r[7][0];                           \
    float a1 = rf0 * m2r[0][1] + rf1 * m2r[1][1] + rf2 * m2r[2][1] +        \
               rf3 * m2r[3][1] + rf4 * m2r[4][1] + rf5 * m2r[5][1] +        \
               rf6 * m2r[6][1] + rf7 * m2r[7][1];                           \
    float a2 = rf0 * m2r[0][2] + rf1 * m2r[1][2] + rf2 * m2r[2][2] +        \
               rf3 * m2r[3][2] + rf4 * m2r[4][2] + rf5 * m2r[5][2] +        \
               rf6 * m2r[6][2] + rf7 * m2r[7][2];                           \
    float a3 = rf0 * m2r[0][3] + rf1 * m2r[1][3] + rf2 * m2r[2][3] +        \
               rf3 * m2r[3][3] + rf4 * m2r[4][3] + rf5 * m2r[5][3] +        \
               rf6 * m2r[6][3] + rf7 * m2r[7][3];                           \
    uint32_t p0 = cvtpk_bf16(a0, a1), p1 = cvtpk_bf16(a2, a3);              \
    *(uint2*)&s_A[B][(eL << 5) + ((hq << 2) ^ asw)] = make_uint2(p0, p1);   \
  }

  f32x4 acc00 = {0.f, 0.f, 0.f, 0.f}, acc01 = acc00, acc10 = acc00, acc11 = acc00;

  LOAD_M2(0);
  __syncthreads();   // rs visible (one-time full drain is fine)

  // produce A(0); prefetch W chunks 0,1 and rs for i=1
  {
    uint4 rs0 = *(const uint4*)&s_rs[(eL << 9) + (0 ^ esw8)];
    PRODUCE_A_FROM(rs0, 0);
  }
  bf16x8 bvA0 = *(const bf16x8*)(W2T + bvb0 + WOFF(0));
  bf16x8 bvA1 = *(const bf16x8*)(W2T + bvb1 + WOFF(0));
  bf16x8 bvB0 = *(const bf16x8*)(W2T + bvb0 + WOFF(1));
  bf16x8 bvB1 = *(const bf16x8*)(W2T + bvb1 + WOFF(1));
  uint4 rsA = *(const uint4*)&s_rs[(eL << 9) + ((1 << 3) ^ esw8)];
  uint4 rsB = rsA;
  asm volatile("s_waitcnt lgkmcnt(0)" ::: "memory");
  __builtin_amdgcn_s_barrier();

  // ---- main loop, 2x unrolled: even half uses s_A[0]/bvA/rsA, odd uses s_A[1]/bvB/rsB
  for (int cc = 0; cc < NCHUNK; cc += 2) {
    {  // ---- c = cc (even)
      int c = cc;
      bf16x8 af0 = *(const bf16x8*)&s_A[0][aidx0];
      bf16x8 af1 = *(const bf16x8*)&s_A[0][aidx1];
      if (c + 2 < NCHUNK)
        rsB = *(const uint4*)&s_rs[(eL << 9) + ((((c + 2) & 63) << 3) ^ esw8)];
      if (((c + 1) & 63) == 0) LOAD_M2((c + 1) >> 6);
      if (c + 1 < NCHUNK) PRODUCE_A_FROM(rsA, 1);
      acc00 = __builtin_amdgcn_mfma_f32_16x16x32_bf16(af0, bvA0, acc00, 0, 0, 0);
      acc01 = __builtin_amdgcn_mfma_f32_16x16x32_bf16(af0, bvA1, acc01, 0, 0, 0);
      acc10 = __builtin_amdgcn_mfma_f32_16x16x32_bf16(af1, bvA0, acc10, 0, 0, 0);
      acc11 = __builtin_amdgcn_mfma_f32_16x16x32_bf16(af1, bvA1, acc11, 0, 0, 0);
      if (c + 2 < NCHUNK) {
        bvA0 = *(const bf16x8*)(W2T + bvb0 + WOFF(c + 2));
        bvA1 = *(const bf16x8*)(W2T + bvb1 + WOFF(c + 2));
      }
      asm volatile("s_waitcnt lgkmcnt(0)" ::: "memory");
      __builtin_amdgcn_s_barrier();
    }
    {  // ---- c = cc + 1 (odd)
      int c = cc + 1;
      bf16x8 af0 = *(const bf16x8*)&s_A[1][aidx0];
      bf16x8 af1 = *(const bf16x8*)&s_A[1][aidx1];
      if (c + 2 < NCHUNK)
        rsA = *(const uint4*)&s_rs[(eL << 9) + ((((c + 2) & 63) << 3) ^ esw8)];
      if (((c + 1) & 63) == 0) LOAD_M2((c + 1) >> 6);
      if (c + 1 < NCHUNK) PRODUCE_A_FROM(rsB, 0);
      acc00 = __builtin_amdgcn_mfma_f32_16x16x32_bf16(af0, bvB0, acc00, 0, 0, 0);
      acc01 = __builtin_amdgcn_mfma_f32_16x16x32_bf16(af0, bvB1, acc01, 0, 0, 0);
      acc10 = __builtin_amdgcn_mfma_f32_16x16x32_bf16(af1, bvB0, acc10, 0, 0, 0);
      acc11 = __builtin_amdgcn_mfma_f32_16x16x32_bf16(af1, bvB1, acc11, 0, 0, 0);
      if (c + 2 < NCHUNK) {
        bvB0 = *(const bf16x8*)(W2T + bvb0 + WOFF(c + 2));
        bvB1 = *(const bf16x8*)(W2T + bvb1 + WOFF(c + 2));
      }
      asm volatile("s_waitcnt lgkmcnt(0)" ::: "memory");
      __builtin_amdgcn_s_barrier();
    }
  }

  // ---- epilogue: C/D layout col = lane&15, row = (lane>>4)*4 + reg
  {
    int row0 = e0 + ew * 32 + lg * 4;
#pragma unroll
    for (int r = 0; r < 4; ++r) {
      int rowa = row0 + r, rowb = row0 + 16 + r;
      int col0 = ow * 32 + lr, col1 = col0 + 16;
      if (rowa < E) {
        out[(size_t)rowa * OUTD + col0] = acc00[r];
        out[(size_t)rowa * OUTD + col1] = acc01[r];
      }
      if (rowb < E) {
        out[(size_t)rowb * OUTD + col0] = acc10[r];
        out[(size_t)rowb * OUTD + col1] = acc11[r];
      }
    }
  }
}

extern "C" void kernel_launch(void* const* d_in, const int* in_sizes, int n_in,
                              void* d_out, int out_size, void* d_ws, size_t ws_size,
                              hipStream_t stream) {
  const float* rbf = (const float*)d_in[0];
  const float* sph = (const float*)d_in[1];
  const float* m   = (const float*)d_in[2];
  const float* W   = (const float*)d_in[3];
  const int* id_reduce = (const int*)d_in[4];
  const int* id_ragged = (const int*)d_in[5];
  float* out = (float*)d_out;

  int E = in_sizes[0] / (INTERM * SPH_N);   // 30000
  int nTrip = in_sizes[2] / EMB;            // 240000

  char* ws = (char*)d_ws;
  int* inv = (int*)ws;                                       // <1 MB
  unsigned short* W2T = (unsigned short*)(ws + (1u << 20));  // 2 MB

  hipMemsetAsync(inv, 0xFF, (size_t)E * KMAX * sizeof(int), stream);
  k_build_inv<<<(nTrip + 255) / 256, 256, 0, stream>>>(id_reduce, id_ragged, inv, nTrip, E);
  k_w2t<<<(OUTD * KDIM) / 256, 256, 0, stream>>>(W, W2T);

  int nblk = (E + EB - 1) / EB;   // 469
  k_fused<<<nblk, NTHR, 0, stream>>>(rbf, sph, m, inv, W2T, out, E);
}

// Round 6
// 211.453 us; speedup vs baseline: 2.2860x; 1.4158x over previous
//
#include <hip/hip_runtime.h>
#include <stdint.h>

// out[e,o] = sum_{i,h} A[e,i,h] * W[h,i,o],  A[e] = rbf[e] @ sph[e] @ m2[e]
// Fully fused, chunk c = (hw = c>>6, i = c&63), K=32 per chunk:
//   prolog: rs[e,i,k] = sum_s rbf[e,i,s] sphT[e,k,s]  -> LDS bf16 (swizzled, intra-wave)
//   per chunk: A_c[e, 32h] = sum_k rs[e,i,k] m2[e,k,hw*32+h]  (VALU) -> LDS dbuf
//              acc += A_c @ W_c  (mfma 16x16x32; W via asm global_load, counted vmcnt(1))
// All hot-loop VMEM is inline-asm global_load (escapes lgkmcnt); 1x8 wave grid (no bv dup).

#define EMB 128
#define INTERM 64
#define SPH_N 16
#define KMAX 8
#define OUTD 128
#define KDIM 8192
#define EB 64
#define NTHR 512
#define NCHUNK 256

typedef __attribute__((ext_vector_type(8))) short bf16x8;
typedef __attribute__((ext_vector_type(4))) float f32x4;
typedef __attribute__((ext_vector_type(4))) int i32x4;

__device__ __forceinline__ unsigned short f32_to_bf16(float f) {
  union { float f; uint32_t u; } v; v.f = f;
  uint32_t r = (v.u + 0x7fffu + ((v.u >> 16) & 1u)) >> 16;
  return (unsigned short)r;
}
__device__ __forceinline__ uint32_t cvtpk_bf16(float lo, float hi) {
  uint32_t r;
  asm("v_cvt_pk_bf16_f32 %0, %1, %2" : "=v"(r) : "v"(lo), "v"(hi));
  return r;
}
__device__ __forceinline__ float bf16lo_f(uint32_t u) { return __uint_as_float(u << 16); }
__device__ __forceinline__ float bf16hi_f(uint32_t u) { return __uint_as_float(u & 0xffff0000u); }
__device__ __forceinline__ bf16x8 as_bf(f32x4 v) {
  union { f32x4 f; bf16x8 b; } u; u.f = v; return u.b;
}
// W load: 32-bit lane voffset + uniform SGPR base (asm => not lgkmcnt-counted)
__device__ __forceinline__ void gload_bv(f32x4& d, const unsigned short* sbase, uint32_t voff) {
  asm volatile("global_load_dwordx4 %0, %1, %2" : "=&v"(d) : "v"(voff), "s"(sbase));
}

__global__ void k_build_inv(const int* __restrict__ id_reduce,
                            const int* __restrict__ id_ragged,
                            int* __restrict__ inv, int nTrip, int E) {
  int t = blockIdx.x * blockDim.x + threadIdx.x;
  if (t >= nTrip) return;
  int e = id_reduce[t], k = id_ragged[t];
  if (e >= 0 && e < E && k >= 0 && k < KMAX) inv[e * KMAX + k] = t;
}

__global__ void k_w2t(const float* __restrict__ W, unsigned short* __restrict__ W2T) {
  int idx = blockIdx.x * blockDim.x + threadIdx.x;  // [0, 128*8192)
  int o = idx >> 13;
  int c = idx & (KDIM - 1);
  int h = c & 127, i = c >> 7;
  W2T[idx] = f32_to_bf16(W[(h * INTERM + i) * OUTD + o]);
}

// sphT[e][k][s] = sph[e][s][k]  (coalesce rs-production loads)
__global__ void k_spht(const float* __restrict__ sph, float* __restrict__ sphT, int E) {
  int idx = blockIdx.x * blockDim.x + threadIdx.x;  // [0, E*128)
  int e = idx >> 7, r = idx & 127;
  if (e >= E) return;
  int k = r >> 4, s = r & 15;
  sphT[(size_t)e * 128 + k * 16 + s] = sph[(size_t)e * 128 + s * 8 + k];
}

__global__ __launch_bounds__(NTHR, 4) void k_fused(
    const float* __restrict__ rbf,   // [E][64][16]
    const float* __restrict__ sphT,  // [Epad][8][16]
    const float* __restrict__ m,     // [nTrip][128]
    const int* __restrict__ inv,     // [Epad][8]
    const unsigned short* __restrict__ W2T,  // [128][8192]
    float* __restrict__ out, int E)
{
  __shared__ unsigned short s_rs[EB * 64 * 8];  // 64 KB, rs[e][i][k] xor-swizzled
  __shared__ unsigned short s_A[2][EB * 32];    // 2 x 4 KB, A-chunk dbuf swizzled

  int tid = threadIdx.x;
  int e0 = blockIdx.x * EB;
  int eL = tid >> 3;          // 0..63 edge-local
  int kq = tid & 7;           // prolog: k ; main: h-quarter (4 h)
  int hq = kq;
  int eg = e0 + eL;
  bool ev = (eg < E);
  int esw8 = (eL & 7) << 3;   // rs swizzle (ushort units)
  int asw  = (eL & 3) << 3;   // A swizzle (ushort units)

  // ---- prolog: rs[eL][i][kq] for all i (intra-wave producer/consumer, no barrier)
  {
    f32x4 sp0 = 0.f, sp1 = 0.f, sp2 = 0.f, sp3 = 0.f;
    if (ev) {
      const f32x4* sp = (const f32x4*)(sphT + (size_t)eg * 128 + kq * 16);
      sp0 = sp[0]; sp1 = sp[1]; sp2 = sp[2]; sp3 = sp[3];
    }
    const f32x4* rb = (const f32x4*)(rbf + (size_t)eg * 1024);
#pragma unroll 4
    for (int i = 0; i < 64; ++i) {
      float v = 0.f;
      if (ev) {
        f32x4 q0 = rb[i * 4 + 0], q1 = rb[i * 4 + 1];
        f32x4 q2 = rb[i * 4 + 2], q3 = rb[i * 4 + 3];
        v = q0.x * sp0.x + q0.y * sp0.y + q0.z * sp0.z + q0.w * sp0.w
          + q1.x * sp1.x + q1.y * sp1.y + q1.z * sp1.z + q1.w * sp1.w
          + q2.x * sp2.x + q2.y * sp2.y + q2.z * sp2.z + q2.w * sp2.w
          + q3.x * sp3.x + q3.y * sp3.y + q3.z * sp3.z + q3.w * sp3.w;
      }
      s_rs[(eL << 9) + (((i << 3) ^ esw8) | kq)] = f32_to_bf16(v);
    }
  }

  // ---- GEMM roles: 8 waves, 1x8 grid; wave tile 64e x 16o (bv has no dup)
  int wid = tid >> 6, lane = tid & 63;
  int lr = lane & 15, lg = lane >> 4;
  int aidx0 = ((0 * 16 + lr) << 5) + ((lg << 3) ^ ((lr & 3) << 3));
  int aidx1 = ((1 * 16 + lr) << 5) + ((lg << 3) ^ ((lr & 3) << 3));
  int aidx2 = ((2 * 16 + lr) << 5) + ((lg << 3) ^ ((lr & 3) << 3));
  int aidx3 = ((3 * 16 + lr) << 5) + ((lg << 3) ^ ((lr & 3) << 3));
  uint32_t voff = (uint32_t)((((wid * 16 + lr) * KDIM) + lg * 8) * 2);

  float m2r[8][4];

#define LOAD_M2(HW)                                                              \
  {                                                                              \
    i32x4 iv0, iv1;                                                              \
    const int* ip_ = inv + (size_t)eg * 8;                                       \
    asm volatile("global_load_dwordx4 %0, %1, off" : "=&v"(iv0) : "v"(ip_));     \
    asm volatile("global_load_dwordx4 %0, %1, off" : "=&v"(iv1) : "v"(ip_ + 4)); \
    asm volatile("s_waitcnt vmcnt(0)" : "+v"(iv0), "+v"(iv1));                   \
    int tk_[8] = {iv0.x, iv0.y, iv0.z, iv0.w, iv1.x, iv1.y, iv1.z, iv1.w};       \
    f32x4 mm_[8];                                                                \
    _Pragma("unroll")                                                            \
    for (int k = 0; k < 8; ++k) {                                                \
      const float* mp_ = m + (size_t)(tk_[k] < 0 ? 0 : tk_[k]) * EMB             \
                         + (HW) * 32 + hq * 4;                                   \
      asm volatile("global_load_dwordx4 %0, %1, off" : "=&v"(mm_[k]) : "v"(mp_));\
    }                                                                            \
    asm volatile("s_waitcnt vmcnt(0)"                                            \
                 : "+v"(mm_[0]), "+v"(mm_[1]), "+v"(mm_[2]), "+v"(mm_[3]),       \
                   "+v"(mm_[4]), "+v"(mm_[5]), "+v"(mm_[6]), "+v"(mm_[7]));      \
    _Pragma("unroll")                                                            \
    for (int k = 0; k < 8; ++k) {                                                \
      bool z_ = tk_[k] < 0;                                                      \
      m2r[k][0] = z_ ? 0.f : mm_[k].x; m2r[k][1] = z_ ? 0.f : mm_[k].y;          \
      m2r[k][2] = z_ ? 0.f : mm_[k].z; m2r[k][3] = z_ ? 0.f : mm_[k].w;          \
    }                                                                            \
  }

#define PRODUCE(RR, B)                                                       \
  {                                                                          \
    float rf0 = bf16lo_f(RR.x), rf1 = bf16hi_f(RR.x);                        \
    float rf2 = bf16lo_f(RR.y), rf3 = bf16hi_f(RR.y);                        \
    float rf4 = bf16lo_f(RR.z), rf5 = bf16hi_f(RR.z);                        \
    float rf6 = bf16lo_f(RR.w), rf7 = bf16hi_f(RR.w);                        \
    float a0 = rf0 * m2r[0][0] + rf1 * m2r[1][0] + rf2 * m2r[2][0] +         \
               rf3 * m2r[3][0] + rf4 * m2r[4][0] + rf5 * m2r[5][0] +         \
               rf6 * m2r[6][0] + rf7 * m2r[7][0];                            \
    float a1 = rf0 * m2r[0][1] + rf1 * m2r[1][1] + rf2 * m2r[2][1] +         \
               rf3 * m2r[3][1] + rf4 * m2r[4][1] + rf5 * m2r[5][1] +         \
               rf6 * m2r[6][1] + rf7 * m2r[7][1];                            \
    float a2 = rf0 * m2r[0][2] + rf1 * m2r[1][2] + rf2 * m2r[2][2] +         \
               rf3 * m2r[3][2] + rf4 * m2r[4][2] + rf5 * m2r[5][2] +         \
               rf6 * m2r[6][2] + rf7 * m2r[7][2];                            \
    float a3 = rf0 * m2r[0][3] + rf1 * m2r[1][3] + rf2 * m2r[2][3] +         \
               rf3 * m2r[3][3] + rf4 * m2r[4][3] + rf5 * m2r[5][3] +         \
               rf6 * m2r[6][3] + rf7 * m2r[7][3];                            \
    uint32_t p0 = cvtpk_bf16(a0, a1), p1 = cvtpk_bf16(a2, a3);               \
    *(uint2*)&s_A[B][(eL << 5) + ((hq << 2) ^ asw)] = make_uint2(p0, p1);    \
  }

  f32x4 acc0 = {0.f, 0.f, 0.f, 0.f}, acc1 = acc0, acc2 = acc0, acc3 = acc0;
  f32x4 bvA, bvB;
  uint4 rsA, rsB;

  LOAD_M2(0)
  // produce A(0); preload rs(1); issue bv(0), bv(1)
  {
    uint4 rs0 = *(const uint4*)&s_rs[(eL << 9) + esw8];
    PRODUCE(rs0, 0)
  }
  rsA = *(const uint4*)&s_rs[(eL << 9) + ((1 << 3) ^ esw8)];
  gload_bv(bvA, W2T + 0, voff);     // WOFF(0)=0
  gload_bv(bvB, W2T + 128, voff);   // WOFF(1)=128
  asm volatile("s_waitcnt lgkmcnt(0)" ::: "memory");
  __builtin_amdgcn_s_barrier();

#define BODY(C, CUR, BVC, BVN, RSP, RSF, WSTR, PF, M2CHK, PROD)                  \
  {                                                                              \
    const int c_ = (C);                                                          \
    bf16x8 af0 = *(const bf16x8*)&s_A[CUR][aidx0];                               \
    bf16x8 af1 = *(const bf16x8*)&s_A[CUR][aidx1];                               \
    bf16x8 af2 = *(const bf16x8*)&s_A[CUR][aidx2];                               \
    bf16x8 af3 = *(const bf16x8*)&s_A[CUR][aidx3];                               \
    RSF = *(const uint4*)&s_rs[(eL << 9) + ((((c_ + 2) & 63) << 3) ^ esw8)];     \
    if (M2CHK && (((c_ + 1) & 63) == 0)) LOAD_M2((c_ + 1) >> 6)                  \
    if (PROD) PRODUCE(RSP, (CUR) ^ 1)                                            \
    asm volatile(WSTR : "+v"(BVC));                                              \
    {                                                                            \
      bf16x8 bvv = as_bf(BVC);                                                   \
      acc0 = __builtin_amdgcn_mfma_f32_16x16x32_bf16(af0, bvv, acc0, 0, 0, 0);   \
      acc1 = __builtin_amdgcn_mfma_f32_16x16x32_bf16(af1, bvv, acc1, 0, 0, 0);   \
      acc2 = __builtin_amdgcn_mfma_f32_16x16x32_bf16(af2, bvv, acc2, 0, 0, 0);   \
      acc3 = __builtin_amdgcn_mfma_f32_16x16x32_bf16(af3, bvv, acc3, 0, 0, 0);   \
    }                                                                            \
    if (PF) {                                                                    \
      uint32_t wo_ = (uint32_t)((((c_ + 2) & 63) << 7) + (((c_ + 2) >> 6) << 5));\
      gload_bv(BVN, W2T + wo_, voff);                                            \
    }                                                                            \
    asm volatile("s_waitcnt lgkmcnt(0)" ::: "memory");                           \
    __builtin_amdgcn_s_barrier();                                                \
  }

  for (int cc = 0; cc < NCHUNK - 2; cc += 2) {
    BODY(cc,     0, bvA, bvA, rsA, rsB, "s_waitcnt vmcnt(1)", 1, 0, 1)
    BODY(cc + 1, 1, bvB, bvB, rsB, rsA, "s_waitcnt vmcnt(1)", 1, 1, 1)
  }
  BODY(NCHUNK - 2, 0, bvA, bvA, rsA, rsB, "s_waitcnt vmcnt(1)", 0, 0, 1)
  BODY(NCHUNK - 1, 1, bvB, bvB, rsB, rsA, "s_waitcnt vmcnt(0)", 0, 0, 0)

  // ---- epilogue: C/D layout col = lane&15, row = (lane>>4)*4 + reg
  {
    int col = wid * 16 + lr;
#pragma unroll
    for (int r = 0; r < 4; ++r) {
      int rb_ = e0 + lg * 4 + r;
      if (rb_ + 0 < E)  out[(size_t)(rb_ + 0)  * OUTD + col] = acc0[r];
      if (rb_ + 16 < E) out[(size_t)(rb_ + 16) * OUTD + col] = acc1[r];
      if (rb_ + 32 < E) out[(size_t)(rb_ + 32) * OUTD + col] = acc2[r];
      if (rb_ + 48 < E) out[(size_t)(rb_ + 48) * OUTD + col] = acc3[r];
    }
  }
}

extern "C" void kernel_launch(void* const* d_in, const int* in_sizes, int n_in,
                              void* d_out, int out_size, void* d_ws, size_t ws_size,
                              hipStream_t stream) {
  const float* rbf = (const float*)d_in[0];
  const float* sph = (const float*)d_in[1];
  const float* m   = (const float*)d_in[2];
  const float* W   = (const float*)d_in[3];
  const int* id_reduce = (const int*)d_in[4];
  const int* id_ragged = (const int*)d_in[5];
  float* out = (float*)d_out;

  int E = in_sizes[0] / (INTERM * SPH_N);   // 30000
  int nTrip = in_sizes[2] / EMB;            // 240000
  int nblk = (E + EB - 1) / EB;             // 469
  int Epad = nblk * EB;                     // 30016

  char* ws = (char*)d_ws;
  int* inv = (int*)ws;                                       // [0, 1 MB)
  unsigned short* W2T = (unsigned short*)(ws + (1u << 20));  // [1, 3 MB)
  float* sphT = (float*)(ws + (3u << 20));                   // [3, ~18.4 MB)

  hipMemsetAsync(inv, 0xFF, (size_t)Epad * KMAX * sizeof(int), stream);
  k_build_inv<<<(nTrip + 255) / 256, 256, 0, stream>>>(id_reduce, id_ragged, inv, nTrip, E);
  k_w2t<<<(OUTD * KDIM) / 256, 256, 0, stream>>>(W, W2T);
  k_spht<<<(E * 128 + 255) / 256, 256, 0, stream>>>(sph, sphT, E);

  k_fused<<<nblk, NTHR, 0, stream>>>(rbf, sphT, m, inv, W2T, out, E);
}